// Round 2
// baseline (6469.237 us; speedup 1.0000x reference)
//
#include <hip/hip_runtime.h>
#include <hip/hip_bf16.h>

// Problem constants
#define Bsz 8
#define Lseq 2048
#define Dm 1024
#define Pst 256
#define BL (Bsz*Lseq)   // 16384

__device__ __forceinline__ float4 ldg4(const float* p){ return *reinterpret_cast<const float4*>(p); }

// ---------------- small projection: out[b,j] = bias[j] + sum_d t[b,d]*W[d,j] ----------------
__global__ __launch_bounds__(256) void proj_k(
    const float* __restrict__ T, const float* __restrict__ W,
    const float* __restrict__ bias, float* __restrict__ Out, int N)
{
    __shared__ float ts[Dm];
    int b = blockIdx.y;
    int j = blockIdx.x * 256 + threadIdx.x;
    for (int i = threadIdx.x; i < Dm; i += 256) ts[i] = T[b*Dm + i];
    __syncthreads();
    float s = bias[j];
    #pragma unroll 4
    for (int d = 0; d < Dm; ++d) s += ts[d] * W[(size_t)d*N + j];
    Out[(size_t)b*N + j] = s;
}

// ---------------- SSM setup: Lam_bar and B_bar^T (D x 2P: [re | im]) ----------------
__global__ __launch_bounds__(256) void ssm_setup_k(
    const float* __restrict__ Lam_re, const float* __restrict__ Lam_im,
    const float* __restrict__ B_re, const float* __restrict__ B_im,
    const float* __restrict__ log_step, float* __restrict__ lam, float* __restrict__ BbarT)
{
    int d = blockIdx.x;      // 0..1023
    int p = threadIdx.x;     // 0..255
    float lr = Lam_re[p], li = Lam_im[p];
    float dt = expf(log_step[p]);
    float e  = expf(lr*dt);
    float cr = e * cosf(li*dt);
    float ci = e * sinf(li*dt);
    float d2 = lr*lr + li*li;
    float nr = cr - 1.0f, ni = ci;
    float gr = (nr*lr + ni*li) / d2;
    float gi = (ni*lr - nr*li) / d2;
    float br = B_re[(size_t)p*Dm + d], bi = B_im[(size_t)p*Dm + d];
    BbarT[(size_t)d*(2*Pst) + p]        = gr*br - gi*bi;
    BbarT[(size_t)d*(2*Pst) + Pst + p]  = gr*bi + gi*br;
    if (d == 0) { lam[2*p] = cr; lam[2*p+1] = ci; }
}

// ---------------- C concat transpose: Ccat^T (2P x D), rows: 2*C_re then -2*C_im ----------------
__global__ __launch_bounds__(256) void ccat_k(
    const float* __restrict__ C_re, const float* __restrict__ C_im, float* __restrict__ CcatT)
{
    int k = blockIdx.x;  // 0..511
    for (int d = threadIdx.x; d < Dm; d += 256) {
        float v = (k < Pst) ? 2.0f*C_re[(size_t)d*Pst + k] : -2.0f*C_im[(size_t)d*Pst + (k-Pst)];
        CcatT[(size_t)k*Dm + d] = v;
    }
}

// ---------------- LayerNorm + modulate (two variants) ----------------
// MODE 0: out = LN(x)*(1+scale_a[b,d]) + shift_a[b,d]                    (x = y input)
// MODE 1: out = (LN(x)*(1+scale_c)+shift_c)*(1+scale_ff)+shift_ff        (x = y1 in d_out)
template<int MODE>
__global__ __launch_bounds__(256) void ln_mod_k(
    const float* __restrict__ X, float* __restrict__ Y,
    const float* __restrict__ mod, const float* __restrict__ cond)
{
    int row = blockIdx.x;        // b*L + l
    int b = row >> 11;
    int t = threadIdx.x;
    const float* xr = X + (size_t)row*Dm;
    float4 v = ldg4(xr + t*4);
    float s  = v.x + v.y + v.z + v.w;
    float ss = v.x*v.x + v.y*v.y + v.z*v.z + v.w*v.w;
    #pragma unroll
    for (int o = 32; o > 0; o >>= 1) { s += __shfl_down(s, o); ss += __shfl_down(ss, o); }
    __shared__ float red[8];
    int wid = t >> 6;
    if ((t & 63) == 0) { red[wid] = s; red[4+wid] = ss; }
    __syncthreads();
    float S  = red[0]+red[1]+red[2]+red[3];
    float SS = red[4]+red[5]+red[6]+red[7];
    float mean = S * (1.0f/Dm);
    float var  = SS * (1.0f/Dm) - mean*mean;
    float rstd = rsqrtf(var + 1e-5f);
    int d0 = t*4;
    float xv[4] = {v.x, v.y, v.z, v.w};
    float4 o;
    float* op = &o.x;
    #pragma unroll
    for (int q = 0; q < 4; ++q) {
        int d = d0 + q;
        float ln = (xv[q] - mean) * rstd;
        float r;
        if (MODE == 0) {
            r = ln * (1.0f + mod[(size_t)b*6144 + 1024 + d]) + mod[(size_t)b*6144 + d];
        } else {
            float yn = ln * (1.0f + cond[(size_t)b*2048 + d]) + cond[(size_t)b*2048 + 1024 + d];
            r = yn * (1.0f + mod[(size_t)b*6144 + 4096 + d]) + mod[(size_t)b*6144 + 3072 + d];
        }
        op[q] = r;
    }
    *reinterpret_cast<float4*>(Y + (size_t)row*Dm + d0) = o;
}

// ---------------- chunked complex scan over L ----------------
// Bu layout: (BL x 512), row m = b*L + l; col p = re, col 256+p = im.
__global__ __launch_bounds__(256) void scan1_k(
    const float* __restrict__ Bu, const float* __restrict__ lam, float* __restrict__ carry)
{
    int bc = blockIdx.x;            // b*32 + c
    int b = bc >> 5, c = bc & 31;
    int p = threadIdx.x;
    float ar = lam[2*p], ai = lam[2*p+1];
    float xr = 0.f, xi = 0.f;
    const float* base = Bu + ((size_t)(b*Lseq + c*64))*(2*Pst);
    #pragma unroll 4
    for (int i = 0; i < 64; ++i) {
        float br = base[(size_t)i*(2*Pst) + p];
        float bi = base[(size_t)i*(2*Pst) + Pst + p];
        float nxr = ar*xr - ai*xi + br;
        float nxi = ar*xi + ai*xr + bi;
        xr = nxr; xi = nxi;
    }
    carry[((size_t)bc*Pst + p)*2]     = xr;
    carry[((size_t)bc*Pst + p)*2 + 1] = xi;
}

__global__ __launch_bounds__(256) void scan2_k(float* __restrict__ carry, const float* __restrict__ lam)
{
    int b = blockIdx.x;  // 0..7
    int p = threadIdx.x;
    float ar = lam[2*p], ai = lam[2*p+1];
    float pr = ar, pi = ai;             // a^64 by squaring
    #pragma unroll
    for (int s = 0; s < 6; ++s) { float nr = pr*pr - pi*pi, ni = 2.f*pr*pi; pr = nr; pi = ni; }
    float sr = 0.f, si = 0.f;
    for (int c = 0; c < 32; ++c) {
        size_t idx = ((size_t)(b*32 + c)*Pst + p)*2;
        float tr = carry[idx], ti = carry[idx+1];
        carry[idx] = sr; carry[idx+1] = si;     // incoming state for chunk c
        float nr = pr*sr - pi*si + tr;
        float ni = pr*si + pi*sr + ti;
        sr = nr; si = ni;
    }
}

__global__ __launch_bounds__(256) void scan3_k(
    float* __restrict__ Bu, const float* __restrict__ lam, const float* __restrict__ carry)
{
    int bc = blockIdx.x;
    int b = bc >> 5, c = bc & 31;
    int p = threadIdx.x;
    float ar = lam[2*p], ai = lam[2*p+1];
    float xr = carry[((size_t)bc*Pst + p)*2];
    float xi = carry[((size_t)bc*Pst + p)*2 + 1];
    float* base = Bu + ((size_t)(b*Lseq + c*64))*(2*Pst);
    #pragma unroll 4
    for (int i = 0; i < 64; ++i) {
        float br = base[(size_t)i*(2*Pst) + p];
        float bi = base[(size_t)i*(2*Pst) + Pst + p];
        float nxr = ar*xr - ai*xi + br;
        float nxi = ar*xi + ai*xr + bi;
        xr = nxr; xi = nxi;
        base[(size_t)i*(2*Pst) + p] = xr;
        base[(size_t)i*(2*Pst) + Pst + p] = xi;
    }
}

// ---------------- 128x128 tiled fp32 GEMM, 256 threads, 8x8 per thread ----------------
// EPI 0: C[m,n] = acc                                   (Bu)
// EPI 1: out[m,d] = y[m,d] + gate_a[b,d]*(acc + Ddiag[d]*u[m,d])     ep0=y ep1=mod ep2=Ddiag ep3=u
// EPI 2: C[m,n] = gelu_tanh(acc + b1[n])                ep0=b1
// EPI 3: out[m0+m,d] += gate_ff[b,d]*(acc + b2[d])      ep0=b2 ep1=mod
template<int EPI>
__global__ __launch_bounds__(256) void gemm_k(
    const float* __restrict__ A, const float* __restrict__ Bm, float* __restrict__ C,
    int M, int N, int K,
    const float* __restrict__ ep0, const float* __restrict__ ep1,
    const float* __restrict__ ep2, const float* __restrict__ ep3, int m0)
{
    __shared__ float As[16][128];
    __shared__ float Bs[16][128];
    int tid = threadIdx.x;
    int bx = blockIdx.x, by = blockIdx.y;
    int tx = tid & 15, ty = tid >> 4;
    float acc[8][8] = {};
    const float* Ab = A + (size_t)(by*128) * K;
    const float* Bb = Bm + (size_t)bx*128;

    for (int kt = 0; kt < K; kt += 16) {
        #pragma unroll
        for (int i = 0; i < 2; ++i) {
            int f = tid*2 + i;
            int r = f >> 2, c4 = f & 3;
            float4 v = ldg4(Ab + (size_t)r*K + kt + c4*4);
            As[c4*4+0][r] = v.x; As[c4*4+1][r] = v.y; As[c4*4+2][r] = v.z; As[c4*4+3][r] = v.w;
        }
        #pragma unroll
        for (int i = 0; i < 2; ++i) {
            int f = tid*2 + i;
            int r = f >> 5, c4 = f & 31;
            float4 v = ldg4(Bb + (size_t)(kt + r)*N + c4*4);
            *reinterpret_cast<float4*>(&Bs[r][c4*4]) = v;
        }
        __syncthreads();
        #pragma unroll
        for (int k = 0; k < 16; ++k) {
            float4 a0 = *reinterpret_cast<const float4*>(&As[k][ty*8]);
            float4 a1 = *reinterpret_cast<const float4*>(&As[k][ty*8+4]);
            float4 b0 = *reinterpret_cast<const float4*>(&Bs[k][tx*8]);
            float4 b1 = *reinterpret_cast<const float4*>(&Bs[k][tx*8+4]);
            float af[8] = {a0.x,a0.y,a0.z,a0.w,a1.x,a1.y,a1.z,a1.w};
            float bf[8] = {b0.x,b0.y,b0.z,b0.w,b1.x,b1.y,b1.z,b1.w};
            #pragma unroll
            for (int i = 0; i < 8; ++i)
                #pragma unroll
                for (int j = 0; j < 8; ++j)
                    acc[i][j] += af[i]*bf[j];
        }
        __syncthreads();
    }

    int row0 = by*128 + ty*8;
    int col0 = bx*128 + tx*8;
    if (EPI == 0) {
        #pragma unroll
        for (int i = 0; i < 8; ++i) {
            float4 v0 = make_float4(acc[i][0],acc[i][1],acc[i][2],acc[i][3]);
            float4 v1 = make_float4(acc[i][4],acc[i][5],acc[i][6],acc[i][7]);
            *reinterpret_cast<float4*>(C + (size_t)(row0+i)*N + col0)     = v0;
            *reinterpret_cast<float4*>(C + (size_t)(row0+i)*N + col0 + 4) = v1;
        }
    } else if (EPI == 1) {
        #pragma unroll
        for (int i = 0; i < 8; ++i) {
            int m = row0 + i; int b = m >> 11;
            #pragma unroll
            for (int j = 0; j < 8; ++j) {
                int d = col0 + j;
                float v = ep0[(size_t)m*Dm + d]
                        + ep1[(size_t)b*6144 + 2048 + d] * (acc[i][j] + ep2[d]*ep3[(size_t)m*Dm + d]);
                C[(size_t)m*Dm + d] = v;
            }
        }
    } else if (EPI == 2) {
        #pragma unroll
        for (int i = 0; i < 8; ++i) {
            float r[8];
            #pragma unroll
            for (int j = 0; j < 8; ++j) {
                float x = acc[i][j] + ep0[col0 + j];
                float x3 = x*x*x;
                r[j] = 0.5f*x*(1.0f + tanhf(0.7978845608028654f*(x + 0.044715f*x3)));
            }
            float4 v0 = make_float4(r[0],r[1],r[2],r[3]);
            float4 v1 = make_float4(r[4],r[5],r[6],r[7]);
            *reinterpret_cast<float4*>(C + (size_t)(row0+i)*N + col0)     = v0;
            *reinterpret_cast<float4*>(C + (size_t)(row0+i)*N + col0 + 4) = v1;
        }
    } else { // EPI 3
        #pragma unroll
        for (int i = 0; i < 8; ++i) {
            int gm = m0 + row0 + i; int b = gm >> 11;
            #pragma unroll
            for (int j = 0; j < 8; ++j) {
                int d = col0 + j;
                float v = acc[i][j] + ep0[d];
                C[(size_t)gm*Dm + d] += ep1[(size_t)b*6144 + 5120 + d] * v;
            }
        }
    }
}

extern "C" void kernel_launch(void* const* d_in, const int* in_sizes, int n_in,
                              void* d_out, int out_size, void* d_ws, size_t ws_size,
                              hipStream_t stream) {
    const float* y      = (const float*)d_in[0];
    const float* t      = (const float*)d_in[1];
    const float* Wm     = (const float*)d_in[2];
    const float* bm     = (const float*)d_in[3];
    const float* Lam_re = (const float*)d_in[4];
    const float* Lam_im = (const float*)d_in[5];
    const float* B_re   = (const float*)d_in[6];
    const float* B_im   = (const float*)d_in[7];
    const float* C_re   = (const float*)d_in[8];
    const float* C_im   = (const float*)d_in[9];
    const float* Ddiag  = (const float*)d_in[10];
    const float* lstep  = (const float*)d_in[11];
    const float* Wc     = (const float*)d_in[12];
    const float* bcn    = (const float*)d_in[13];
    const float* W1     = (const float*)d_in[14];
    const float* b1     = (const float*)d_in[15];
    const float* W2     = (const float*)d_in[16];
    const float* b2     = (const float*)d_in[17];
    float* out = (float*)d_out;
    char* ws = (char*)d_ws;

    // workspace arena (~101 MB)
    float* u     = (float*)(ws);                      // 64 MB: u, later y2 (aliased)
    float* Bu    = (float*)(ws + 67108864ull);        // 32 MB: Bu -> xs -> h chunks (aliased)
    float* mod   = (float*)(ws + 100663296ull);       // 8x6144
    float* cond  = (float*)(ws + 100859904ull);       // 8x2048
    float* lam   = (float*)(ws + 100925440ull);       // 256x2
    float* BbarT = (float*)(ws + 100927488ull);       // 1024x512
    float* CcatT = (float*)(ws + 103024640ull);       // 512x1024
    float* carry = (float*)(ws + 105121792ull);       // 2048x32x2
    float* y2 = u;     // alias: u dead after Cproj epilogue
    float* h  = Bu;    // alias: xs dead after Cproj GEMM

    // 1) modulation projections
    proj_k<<<dim3(24,8),256,0,stream>>>(t, Wm, bm, mod, 6144);
    proj_k<<<dim3(8,8),256,0,stream>>>(t, Wc, bcn, cond, 2048);
    // 2) SSM parameter prep
    ssm_setup_k<<<1024,256,0,stream>>>(Lam_re, Lam_im, B_re, B_im, lstep, lam, BbarT);
    ccat_k<<<512,256,0,stream>>>(C_re, C_im, CcatT);
    // 3) LN + AdaLN modulate -> u
    ln_mod_k<0><<<BL,256,0,stream>>>(y, u, mod, nullptr);
    // 4) Bu = u @ BbarT   (16384 x 512 x 1024)
    gemm_k<0><<<dim3(4,128),256,0,stream>>>(u, BbarT, Bu, BL, 512, 1024,
                                            nullptr,nullptr,nullptr,nullptr, 0);
    // 5) complex scan over L (in-place Bu -> xs)
    scan1_k<<<256,256,0,stream>>>(Bu, lam, carry);
    scan2_k<<<8,256,0,stream>>>(carry, lam);
    scan3_k<<<256,256,0,stream>>>(Bu, lam, carry);
    // 6) y1 = y + gate_a*(2*Re(xs@Cc) + Ddiag*u) -> d_out   (16384 x 1024 x 512)
    gemm_k<1><<<dim3(8,128),256,0,stream>>>(Bu, CcatT, out, BL, 1024, 512,
                                            y, mod, Ddiag, u, 0);
    // 7) LN + AdaLN + FF modulate -> y2
    ln_mod_k<1><<<BL,256,0,stream>>>(out, y2, mod, cond);
    // 8) FFN, chunked over rows (8 x 2048)
    for (int mc = 0; mc < 8; ++mc) {
        const float* y2c = y2 + (size_t)mc*2048*Dm;
        gemm_k<2><<<dim3(32,16),256,0,stream>>>(y2c, W1, h, 2048, 4096, 1024,
                                                b1, nullptr, nullptr, nullptr, 0);
        gemm_k<3><<<dim3(8,16),256,0,stream>>>(h, W2, out, 2048, 1024, 4096,
                                               b2, mod, nullptr, nullptr, mc*2048);
    }
}

// Round 3
// 1162.105 us; speedup vs baseline: 5.5668x; 5.5668x over previous
//
#include <hip/hip_runtime.h>
#include <hip/hip_bf16.h>

// Problem constants
#define Bsz 8
#define Lseq 2048
#define Dm 1024
#define Pst 256
#define BL (Bsz*Lseq)   // 16384

typedef short bf16x8 __attribute__((ext_vector_type(8)));
typedef float f32x4  __attribute__((ext_vector_type(4)));

__device__ __forceinline__ float4 ldg4(const float* p){ return *reinterpret_cast<const float4*>(p); }
__device__ __forceinline__ ushort f2bf(float f){
    __hip_bfloat16 h = __float2bfloat16(f);
    return *reinterpret_cast<ushort*>(&h);
}
__device__ __forceinline__ float bf2f(ushort u){
    __hip_bfloat16 h = *reinterpret_cast<__hip_bfloat16*>(&u);
    return __bfloat162float(h);
}

// ---------------- small projection: out[b,j] = bias[j] + sum_d t[b,d]*W[d,j] ----------------
__global__ __launch_bounds__(256) void proj_k(
    const float* __restrict__ T, const float* __restrict__ W,
    const float* __restrict__ bias, float* __restrict__ Out, int N)
{
    __shared__ float ts[Dm];
    int b = blockIdx.y;
    int j = blockIdx.x * 256 + threadIdx.x;
    for (int i = threadIdx.x; i < Dm; i += 256) ts[i] = T[b*Dm + i];
    __syncthreads();
    float s = bias[j];
    #pragma unroll 4
    for (int d = 0; d < Dm; ++d) s += ts[d] * W[(size_t)d*N + j];
    Out[(size_t)b*N + j] = s;
}

// ---------------- SSM setup: lam and B_bar as bf16 [2P][D] (GEMM-B layout [n][k]) ----------------
__global__ __launch_bounds__(256) void ssm_setup_k(
    const float* __restrict__ Lam_re, const float* __restrict__ Lam_im,
    const float* __restrict__ B_re, const float* __restrict__ B_im,
    const float* __restrict__ log_step, float* __restrict__ lam, ushort* __restrict__ Bbar_bf)
{
    int p = blockIdx.x;          // 0..255
    float lr = Lam_re[p], li = Lam_im[p];
    float dt = expf(log_step[p]);
    float e  = expf(lr*dt);
    float cr = e * cosf(li*dt);
    float ci = e * sinf(li*dt);
    float d2 = lr*lr + li*li;
    float nr = cr - 1.0f, ni = ci;
    float gr = (nr*lr + ni*li) / d2;
    float gi = (ni*lr - nr*li) / d2;
    if (threadIdx.x == 0) { lam[2*p] = cr; lam[2*p+1] = ci; }
    for (int d = threadIdx.x; d < Dm; d += 256) {
        float br = B_re[(size_t)p*Dm + d], bi = B_im[(size_t)p*Dm + d];
        Bbar_bf[(size_t)p*Dm + d]         = f2bf(gr*br - gi*bi);   // re row p
        Bbar_bf[(size_t)(Pst+p)*Dm + d]   = f2bf(gr*bi + gi*br);   // im row 256+p
    }
}

// ---------------- C concat as bf16 [D][2P] (GEMM-B layout [n][k]): [2C_re | -2C_im] ----------------
__global__ __launch_bounds__(256) void ccat_k(
    const float* __restrict__ C_re, const float* __restrict__ C_im, ushort* __restrict__ Ccat_bf)
{
    int d = blockIdx.x;          // 0..1023
    int p = threadIdx.x;         // 0..255
    Ccat_bf[(size_t)d*(2*Pst) + p]       = f2bf( 2.0f*C_re[(size_t)d*Pst + p]);
    Ccat_bf[(size_t)d*(2*Pst) + Pst + p] = f2bf(-2.0f*C_im[(size_t)d*Pst + p]);
}

// ---------------- transpose fp32 [R][C] -> bf16 [C][R] ----------------
__global__ __launch_bounds__(256) void transp_k(
    const float* __restrict__ in, ushort* __restrict__ out, int R, int C)
{
    __shared__ float tile[32][33];
    int tx = threadIdx.x & 31, ty = threadIdx.x >> 5;
    int r0 = blockIdx.y*32, c0 = blockIdx.x*32;
    #pragma unroll
    for (int j = 0; j < 4; ++j)
        tile[ty + j*8][tx] = in[(size_t)(r0 + ty + j*8)*C + c0 + tx];
    __syncthreads();
    #pragma unroll
    for (int j = 0; j < 4; ++j)
        out[(size_t)(c0 + ty + j*8)*R + r0 + tx] = f2bf(tile[tx][ty + j*8]);
}

// ---------------- LayerNorm + modulate -> bf16 output ----------------
// MODE 0: out = LN(x)*(1+scale_a[b,d]) + shift_a[b,d]
// MODE 1: out = (LN(x)*(1+scale_c)+shift_c)*(1+scale_ff)+shift_ff
template<int MODE>
__global__ __launch_bounds__(256) void ln_mod_k(
    const float* __restrict__ X, ushort* __restrict__ Y,
    const float* __restrict__ mod, const float* __restrict__ cond)
{
    int row = blockIdx.x;        // b*L + l
    int b = row >> 11;
    int t = threadIdx.x;
    const float* xr = X + (size_t)row*Dm;
    float4 v = ldg4(xr + t*4);
    float s  = v.x + v.y + v.z + v.w;
    float ss = v.x*v.x + v.y*v.y + v.z*v.z + v.w*v.w;
    #pragma unroll
    for (int o = 32; o > 0; o >>= 1) { s += __shfl_down(s, o); ss += __shfl_down(ss, o); }
    __shared__ float red[8];
    int wid = t >> 6;
    if ((t & 63) == 0) { red[wid] = s; red[4+wid] = ss; }
    __syncthreads();
    float S  = red[0]+red[1]+red[2]+red[3];
    float SS = red[4]+red[5]+red[6]+red[7];
    float mean = S * (1.0f/Dm);
    float var  = SS * (1.0f/Dm) - mean*mean;
    float rstd = rsqrtf(var + 1e-5f);
    int d0 = t*4;
    float xv[4] = {v.x, v.y, v.z, v.w};
    ushort o4[4];
    #pragma unroll
    for (int q = 0; q < 4; ++q) {
        int d = d0 + q;
        float ln = (xv[q] - mean) * rstd;
        float r;
        if (MODE == 0) {
            r = ln * (1.0f + mod[(size_t)b*6144 + 1024 + d]) + mod[(size_t)b*6144 + d];
        } else {
            float yn = ln * (1.0f + cond[(size_t)b*2048 + d]) + cond[(size_t)b*2048 + 1024 + d];
            r = yn * (1.0f + mod[(size_t)b*6144 + 4096 + d]) + mod[(size_t)b*6144 + 3072 + d];
        }
        o4[q] = f2bf(r);
    }
    *reinterpret_cast<ushort4*>(Y + (size_t)row*Dm + d0) =
        make_ushort4(o4[0], o4[1], o4[2], o4[3]);
}

// ---------------- chunked complex scan over L (fp32, in-place on Bu) ----------------
__global__ __launch_bounds__(256) void scan1_k(
    const float* __restrict__ Bu, const float* __restrict__ lam, float* __restrict__ carry)
{
    int bc = blockIdx.x;            // b*32 + c
    int b = bc >> 5, c = bc & 31;
    int p = threadIdx.x;
    float ar = lam[2*p], ai = lam[2*p+1];
    float xr = 0.f, xi = 0.f;
    const float* base = Bu + ((size_t)(b*Lseq + c*64))*(2*Pst);
    #pragma unroll 4
    for (int i = 0; i < 64; ++i) {
        float br = base[(size_t)i*(2*Pst) + p];
        float bi = base[(size_t)i*(2*Pst) + Pst + p];
        float nxr = ar*xr - ai*xi + br;
        float nxi = ar*xi + ai*xr + bi;
        xr = nxr; xi = nxi;
    }
    carry[((size_t)bc*Pst + p)*2]     = xr;
    carry[((size_t)bc*Pst + p)*2 + 1] = xi;
}

__global__ __launch_bounds__(256) void scan2_k(float* __restrict__ carry, const float* __restrict__ lam)
{
    int b = blockIdx.x;  // 0..7
    int p = threadIdx.x;
    float ar = lam[2*p], ai = lam[2*p+1];
    float pr = ar, pi = ai;             // a^64 by squaring
    #pragma unroll
    for (int s = 0; s < 6; ++s) { float nr = pr*pr - pi*pi, ni = 2.f*pr*pi; pr = nr; pi = ni; }
    float sr = 0.f, si = 0.f;
    for (int c = 0; c < 32; ++c) {
        size_t idx = ((size_t)(b*32 + c)*Pst + p)*2;
        float tr = carry[idx], ti = carry[idx+1];
        carry[idx] = sr; carry[idx+1] = si;     // incoming state for chunk c
        float nr = pr*sr - pi*si + tr;
        float ni = pr*si + pi*sr + ti;
        sr = nr; si = ni;
    }
}

__global__ __launch_bounds__(256) void scan3_k(
    float* __restrict__ Bu, const float* __restrict__ lam, const float* __restrict__ carry)
{
    int bc = blockIdx.x;
    int b = bc >> 5, c = bc & 31;
    int p = threadIdx.x;
    float ar = lam[2*p], ai = lam[2*p+1];
    float xr = carry[((size_t)bc*Pst + p)*2];
    float xi = carry[((size_t)bc*Pst + p)*2 + 1];
    float* base = Bu + ((size_t)(b*Lseq + c*64))*(2*Pst);
    #pragma unroll 4
    for (int i = 0; i < 64; ++i) {
        float br = base[(size_t)i*(2*Pst) + p];
        float bi = base[(size_t)i*(2*Pst) + Pst + p];
        float nxr = ar*xr - ai*xi + br;
        float nxi = ar*xi + ai*xr + bi;
        xr = nxr; xi = nxi;
        base[(size_t)i*(2*Pst) + p] = xr;
        base[(size_t)i*(2*Pst) + Pst + p] = xi;
    }
}

// ---------------- 128x128 MFMA bf16 GEMM (fp32 accumulate), 4 waves 2x2, 4x4 frags/wave ----------
// A: [M][K] fp32 (AFP32=1, converted in staging) or bf16 (AFP32=0). B: bf16 [N][K]. BK=64.
// EPI 0: C[m,n] = acc                                       (fp32, Bu)
// EPI 1: C[m,d] = ep0[m,d] + gate_a*(acc + Ddiag[d]*u_bf)   ep0=y ep1=mod ep2=Ddiag ep3u=u_bf
// EPI 2: ((ushort*)C)[m,n] = bf16(gelu_tanh(acc + b1[n]))   ep0=b1
// EPI 3: C[m0+m,d] += gate_ff*(acc + b2[d])                 ep0=b2 ep1=mod
#define BKP 72   // padded LDS row stride in bf16 elems (144 B)

template<int EPI, int AFP32>
__global__ __launch_bounds__(256) void gemm_mfma_k(
    const void* __restrict__ Av, const ushort* __restrict__ Bt, float* __restrict__ C,
    int M, int N, int K,
    const float* __restrict__ ep0, const float* __restrict__ ep1,
    const float* __restrict__ ep2, const ushort* __restrict__ ep3u, int m0)
{
    __shared__ ushort As[128*BKP];
    __shared__ ushort Bs[128*BKP];
    int tid = threadIdx.x;
    int bx = blockIdx.x, by = blockIdx.y;
    int w = tid >> 6, l = tid & 63;
    int wr = w >> 1, wc = w & 1;
    int lr = l & 15, lk = l >> 4;

    f32x4 acc[4][4];
    #pragma unroll
    for (int i = 0; i < 4; ++i)
        #pragma unroll
        for (int j = 0; j < 4; ++j)
            #pragma unroll
            for (int q = 0; q < 4; ++q) acc[i][j][q] = 0.f;

    const ushort* Ab = (const ushort*)Av;
    const float*  Af = (const float*)Av;

    for (int kt = 0; kt < K; kt += 64) {
        if (AFP32) {
            #pragma unroll
            for (int j = 0; j < 8; ++j) {
                int idx = tid + j*256;          // 0..2047
                int r = idx >> 4, f4 = idx & 15;
                float4 v = ldg4(Af + (size_t)(by*128 + r)*K + kt + f4*4);
                *reinterpret_cast<ushort4*>(&As[r*BKP + f4*4]) =
                    make_ushort4(f2bf(v.x), f2bf(v.y), f2bf(v.z), f2bf(v.w));
            }
        } else {
            #pragma unroll
            for (int j = 0; j < 4; ++j) {
                int idx = tid + j*256;          // 0..1023
                int r = idx >> 3, kc = idx & 7;
                int4 v = *reinterpret_cast<const int4*>(Ab + (size_t)(by*128 + r)*K + kt + kc*8);
                *reinterpret_cast<int4*>(&As[r*BKP + kc*8]) = v;
            }
        }
        #pragma unroll
        for (int j = 0; j < 4; ++j) {
            int idx = tid + j*256;              // 0..1023
            int r = idx >> 3, kc = idx & 7;
            int4 v = *reinterpret_cast<const int4*>(Bt + (size_t)(bx*128 + r)*K + kt + kc*8);
            *reinterpret_cast<int4*>(&Bs[r*BKP + kc*8]) = v;
        }
        __syncthreads();
        #pragma unroll
        for (int mk = 0; mk < 2; ++mk) {
            bf16x8 a[4], b[4];
            #pragma unroll
            for (int mi = 0; mi < 4; ++mi)
                a[mi] = *reinterpret_cast<bf16x8*>(&As[(wr*64 + mi*16 + lr)*BKP + mk*32 + lk*8]);
            #pragma unroll
            for (int ni = 0; ni < 4; ++ni)
                b[ni] = *reinterpret_cast<bf16x8*>(&Bs[(wc*64 + ni*16 + lr)*BKP + mk*32 + lk*8]);
            #pragma unroll
            for (int mi = 0; mi < 4; ++mi)
                #pragma unroll
                for (int ni = 0; ni < 4; ++ni)
                    acc[mi][ni] = __builtin_amdgcn_mfma_f32_16x16x32_bf16(
                        a[mi], b[ni], acc[mi][ni], 0, 0, 0);
        }
        __syncthreads();
    }

    int row0 = by*128 + wr*64;
    int col0 = bx*128 + wc*64;
    #pragma unroll
    for (int mi = 0; mi < 4; ++mi) {
        #pragma unroll
        for (int ni = 0; ni < 4; ++ni) {
            int n = col0 + ni*16 + lr;
            #pragma unroll
            for (int q = 0; q < 4; ++q) {
                int m = row0 + mi*16 + lk*4 + q;
                float v = acc[mi][ni][q];
                if (EPI == 0) {
                    C[(size_t)m*N + n] = v;
                } else if (EPI == 1) {
                    int b = m >> 11;
                    float g  = ep1[(size_t)b*6144 + 2048 + n];
                    float dd = ep2[n];
                    float uu = bf2f(ep3u[(size_t)m*Dm + n]);
                    C[(size_t)m*Dm + n] = ep0[(size_t)m*Dm + n] + g*(v + dd*uu);
                } else if (EPI == 2) {
                    float x = v + ep0[n];
                    float x3 = x*x*x;
                    float r = 0.5f*x*(1.0f + tanhf(0.7978845608028654f*(x + 0.044715f*x3)));
                    ((ushort*)C)[(size_t)m*N + n] = f2bf(r);
                } else { // EPI 3
                    int gm = m0 + m; int b = gm >> 11;
                    float g = ep1[(size_t)b*6144 + 5120 + n];
                    C[(size_t)gm*Dm + n] += g*(v + ep0[n]);
                }
            }
        }
    }
}

extern "C" void kernel_launch(void* const* d_in, const int* in_sizes, int n_in,
                              void* d_out, int out_size, void* d_ws, size_t ws_size,
                              hipStream_t stream) {
    const float* y      = (const float*)d_in[0];
    const float* t      = (const float*)d_in[1];
    const float* Wm     = (const float*)d_in[2];
    const float* bm     = (const float*)d_in[3];
    const float* Lam_re = (const float*)d_in[4];
    const float* Lam_im = (const float*)d_in[5];
    const float* B_re   = (const float*)d_in[6];
    const float* B_im   = (const float*)d_in[7];
    const float* C_re   = (const float*)d_in[8];
    const float* C_im   = (const float*)d_in[9];
    const float* Ddiag  = (const float*)d_in[10];
    const float* lstep  = (const float*)d_in[11];
    const float* Wc     = (const float*)d_in[12];
    const float* bcn    = (const float*)d_in[13];
    const float* W1     = (const float*)d_in[14];
    const float* b1     = (const float*)d_in[15];
    const float* W2     = (const float*)d_in[16];
    const float* b2     = (const float*)d_in[17];
    float* out = (float*)d_out;
    char* ws = (char*)d_ws;

    // workspace arena (~84 MB)
    ushort* u_bf    = (ushort*)ws;                    // 32 MB: u_bf, later y2_bf (aliased)
    float*  Bu      = (float*)(ws + (32ull<<20));     // 32 MB: Bu -> xs, later h_bf (aliased)
    ushort* Bbar_bf = (ushort*)(ws + (64ull<<20));    // 1 MB  [512][1024]
    ushort* Ccat_bf = (ushort*)(ws + (65ull<<20));    // 1 MB  [1024][512]
    ushort* W1t     = (ushort*)(ws + (66ull<<20));    // 8 MB  [4096][1024]
    ushort* W2t     = (ushort*)(ws + (74ull<<20));    // 8 MB  [1024][4096]
    float*  mod     = (float*)(ws + (82ull<<20));     // 8x6144
    float*  cond    = (float*)(ws + (82ull<<20) + 196608);
    float*  lam     = (float*)(ws + (82ull<<20) + 262144);
    float*  carry   = (float*)(ws + (82ull<<20) + 327680);  // 8*32*256*2 fp32
    ushort* y2_bf = u_bf;
    ushort* h_bf  = (ushort*)Bu;   // 4096x4096 bf16 chunk = 32 MB

    // 1) modulation projections (fp32)
    proj_k<<<dim3(24,8),256,0,stream>>>(t, Wm, bm, mod, 6144);
    proj_k<<<dim3(8,8),256,0,stream>>>(t, Wc, bcn, cond, 2048);
    // 2) SSM parameter prep + weight transposes to bf16 [N][K]
    ssm_setup_k<<<256,256,0,stream>>>(Lam_re, Lam_im, B_re, B_im, lstep, lam, Bbar_bf);
    ccat_k<<<1024,256,0,stream>>>(C_re, C_im, Ccat_bf);
    transp_k<<<dim3(128,32),256,0,stream>>>(W1, W1t, 1024, 4096);
    transp_k<<<dim3(32,128),256,0,stream>>>(W2, W2t, 4096, 1024);
    // 3) LN + AdaLN modulate -> u_bf
    ln_mod_k<0><<<BL,256,0,stream>>>(y, u_bf, mod, nullptr);
    // 4) Bu = u @ Bbar^T   (16384 x 512 x 1024, fp32 out)
    gemm_mfma_k<0,0><<<dim3(4,128),256,0,stream>>>(u_bf, Bbar_bf, Bu, BL, 512, 1024,
                                                   nullptr, nullptr, nullptr, nullptr, 0);
    // 5) complex scan over L (fp32, in-place)
    scan1_k<<<256,256,0,stream>>>(Bu, lam, carry);
    scan2_k<<<8,256,0,stream>>>(carry, lam);
    scan3_k<<<256,256,0,stream>>>(Bu, lam, carry);
    // 6) y1 = y + gate_a*(2Re(xs@C) + Ddiag*u) -> d_out  (16384 x 1024 x 512, A fp32)
    gemm_mfma_k<1,1><<<dim3(8,128),256,0,stream>>>(Bu, Ccat_bf, out, BL, 1024, 512,
                                                   y, mod, Ddiag, u_bf, 0);
    // 7) LN + AdaLN + FF modulate -> y2_bf
    ln_mod_k<1><<<BL,256,0,stream>>>(out, y2_bf, mod, cond);
    // 8) FFN, 4 chunks of 4096 rows
    for (int mc = 0; mc < 4; ++mc) {
        const ushort* y2c = y2_bf + (size_t)mc*4096*Dm;
        gemm_mfma_k<2,0><<<dim3(32,32),256,0,stream>>>(y2c, W1t, (float*)h_bf, 4096, 4096, 1024,
                                                       b1, nullptr, nullptr, nullptr, 0);
        gemm_mfma_k<3,0><<<dim3(8,32),256,0,stream>>>(h_bf, W2t, out, 4096, 1024, 4096,
                                                      b2, mod, nullptr, nullptr, mc*4096);
    }
}

// Round 4
// 958.854 us; speedup vs baseline: 6.7468x; 1.2120x over previous
//
#include <hip/hip_runtime.h>
#include <hip/hip_bf16.h>

// Problem constants
#define Bsz 8
#define Lseq 2048
#define Dm 1024
#define Pst 256
#define BL (Bsz*Lseq)   // 16384

typedef short bf16x8 __attribute__((ext_vector_type(8)));
typedef float f32x4  __attribute__((ext_vector_type(4)));

__device__ __forceinline__ float4 ldg4(const float* p){ return *reinterpret_cast<const float4*>(p); }
__device__ __forceinline__ ushort f2bf(float f){
    __hip_bfloat16 h = __float2bfloat16(f);
    return *reinterpret_cast<ushort*>(&h);
}
__device__ __forceinline__ float bf2f(ushort u){
    __hip_bfloat16 h = *reinterpret_cast<__hip_bfloat16*>(&u);
    return __bfloat162float(h);
}

// ---------------- split-K projection: Out[b,j] += sum_{d in chunk} t[b,d]*W[d,j] (+bias) --------
// grid: (N/256, 8). Each d-chunk is 128 rows. Out must be zeroed before launch.
__global__ __launch_bounds__(256) void proj2_k(
    const float* __restrict__ T, const float* __restrict__ W,
    const float* __restrict__ bias, float* __restrict__ Out, int N)
{
    __shared__ float ts[8][128];
    int j = blockIdx.x*256 + threadIdx.x;
    int d0 = blockIdx.y*128;
    for (int i = threadIdx.x; i < 8*128; i += 256) {
        int b = i >> 7, d = i & 127;
        ts[b][d] = T[(size_t)b*Dm + d0 + d];
    }
    __syncthreads();
    float acc[8] = {};
    #pragma unroll 4
    for (int d = 0; d < 128; ++d) {
        float w = W[(size_t)(d0 + d)*N + j];
        #pragma unroll
        for (int b = 0; b < 8; ++b) acc[b] += ts[b][d]*w;
    }
    float bv = (blockIdx.y == 0) ? bias[j] : 0.f;
    #pragma unroll
    for (int b = 0; b < 8; ++b)
        atomicAdd(&Out[(size_t)b*N + j], acc[b] + bv);
}

// ---------------- SSM setup: lam and B_bar as bf16 [2P][D] (GEMM-B layout [n][k]) ----------------
__global__ __launch_bounds__(256) void ssm_setup_k(
    const float* __restrict__ Lam_re, const float* __restrict__ Lam_im,
    const float* __restrict__ B_re, const float* __restrict__ B_im,
    const float* __restrict__ log_step, float* __restrict__ lam, ushort* __restrict__ Bbar_bf)
{
    int p = blockIdx.x;          // 0..255
    float lr = Lam_re[p], li = Lam_im[p];
    float dt = expf(log_step[p]);
    float e  = expf(lr*dt);
    float cr = e * cosf(li*dt);
    float ci = e * sinf(li*dt);
    float d2 = lr*lr + li*li;
    float nr = cr - 1.0f, ni = ci;
    float gr = (nr*lr + ni*li) / d2;
    float gi = (ni*lr - nr*li) / d2;
    if (threadIdx.x == 0) { lam[2*p] = cr; lam[2*p+1] = ci; }
    for (int d = threadIdx.x; d < Dm; d += 256) {
        float br = B_re[(size_t)p*Dm + d], bi = B_im[(size_t)p*Dm + d];
        Bbar_bf[(size_t)p*Dm + d]         = f2bf(gr*br - gi*bi);   // re row p
        Bbar_bf[(size_t)(Pst+p)*Dm + d]   = f2bf(gr*bi + gi*br);   // im row 256+p
    }
}

// ---------------- C concat as bf16 [D][2P] (GEMM-B layout [n][k]): [2C_re | -2C_im] ----------------
__global__ __launch_bounds__(256) void ccat_k(
    const float* __restrict__ C_re, const float* __restrict__ C_im, ushort* __restrict__ Ccat_bf)
{
    int d = blockIdx.x;          // 0..1023
    int p = threadIdx.x;         // 0..255
    Ccat_bf[(size_t)d*(2*Pst) + p]       = f2bf( 2.0f*C_re[(size_t)d*Pst + p]);
    Ccat_bf[(size_t)d*(2*Pst) + Pst + p] = f2bf(-2.0f*C_im[(size_t)d*Pst + p]);
}

// ---------------- transpose fp32 [R][C] -> bf16 [C][R] ----------------
__global__ __launch_bounds__(256) void transp_k(
    const float* __restrict__ in, ushort* __restrict__ out, int R, int C)
{
    __shared__ float tile[32][33];
    int tx = threadIdx.x & 31, ty = threadIdx.x >> 5;
    int r0 = blockIdx.y*32, c0 = blockIdx.x*32;
    #pragma unroll
    for (int j = 0; j < 4; ++j)
        tile[ty + j*8][tx] = in[(size_t)(r0 + ty + j*8)*C + c0 + tx];
    __syncthreads();
    #pragma unroll
    for (int j = 0; j < 4; ++j)
        out[(size_t)(c0 + ty + j*8)*R + r0 + tx] = f2bf(tile[tx][ty + j*8]);
}

// ---------------- LayerNorm + modulate -> bf16 output ----------------
// MODE 0: out = LN(x)*(1+scale_a[b,d]) + shift_a[b,d]
// MODE 1: out = (LN(x)*(1+scale_c)+shift_c)*(1+scale_ff)+shift_ff
template<int MODE>
__global__ __launch_bounds__(256) void ln_mod_k(
    const float* __restrict__ X, ushort* __restrict__ Y,
    const float* __restrict__ mod, const float* __restrict__ cond)
{
    int row = blockIdx.x;        // b*L + l
    int b = row >> 11;
    int t = threadIdx.x;
    const float* xr = X + (size_t)row*Dm;
    float4 v = ldg4(xr + t*4);
    float s  = v.x + v.y + v.z + v.w;
    float ss = v.x*v.x + v.y*v.y + v.z*v.z + v.w*v.w;
    #pragma unroll
    for (int o = 32; o > 0; o >>= 1) { s += __shfl_down(s, o); ss += __shfl_down(ss, o); }
    __shared__ float red[8];
    int wid = t >> 6;
    if ((t & 63) == 0) { red[wid] = s; red[4+wid] = ss; }
    __syncthreads();
    float S  = red[0]+red[1]+red[2]+red[3];
    float SS = red[4]+red[5]+red[6]+red[7];
    float mean = S * (1.0f/Dm);
    float var  = SS * (1.0f/Dm) - mean*mean;
    float rstd = rsqrtf(var + 1e-5f);
    int d0 = t*4;
    float xv[4] = {v.x, v.y, v.z, v.w};
    ushort o4[4];
    #pragma unroll
    for (int q = 0; q < 4; ++q) {
        int d = d0 + q;
        float ln = (xv[q] - mean) * rstd;
        float r;
        if (MODE == 0) {
            r = ln * (1.0f + mod[(size_t)b*6144 + 1024 + d]) + mod[(size_t)b*6144 + d];
        } else {
            float yn = ln * (1.0f + cond[(size_t)b*2048 + d]) + cond[(size_t)b*2048 + 1024 + d];
            r = yn * (1.0f + mod[(size_t)b*6144 + 4096 + d]) + mod[(size_t)b*6144 + 3072 + d];
        }
        o4[q] = f2bf(r);
    }
    *reinterpret_cast<ushort4*>(Y + (size_t)row*Dm + d0) =
        make_ushort4(o4[0], o4[1], o4[2], o4[3]);
}

// ---------------- chunked complex scan over L (fp32, in-place on Bu) ----------------
__global__ __launch_bounds__(256) void scan1_k(
    const float* __restrict__ Bu, const float* __restrict__ lam, float* __restrict__ carry)
{
    int bc = blockIdx.x;            // b*32 + c
    int b = bc >> 5, c = bc & 31;
    int p = threadIdx.x;
    float ar = lam[2*p], ai = lam[2*p+1];
    float xr = 0.f, xi = 0.f;
    const float* base = Bu + ((size_t)(b*Lseq + c*64))*(2*Pst);
    #pragma unroll 4
    for (int i = 0; i < 64; ++i) {
        float br = base[(size_t)i*(2*Pst) + p];
        float bi = base[(size_t)i*(2*Pst) + Pst + p];
        float nxr = ar*xr - ai*xi + br;
        float nxi = ar*xi + ai*xr + bi;
        xr = nxr; xi = nxi;
    }
    carry[((size_t)bc*Pst + p)*2]     = xr;
    carry[((size_t)bc*Pst + p)*2 + 1] = xi;
}

__global__ __launch_bounds__(256) void scan2_k(float* __restrict__ carry, const float* __restrict__ lam)
{
    int b = blockIdx.x;  // 0..7
    int p = threadIdx.x;
    float ar = lam[2*p], ai = lam[2*p+1];
    float pr = ar, pi = ai;             // a^64 by squaring
    #pragma unroll
    for (int s = 0; s < 6; ++s) { float nr = pr*pr - pi*pi, ni = 2.f*pr*pi; pr = nr; pi = ni; }
    float sr = 0.f, si = 0.f;
    for (int c = 0; c < 32; ++c) {
        size_t idx = ((size_t)(b*32 + c)*Pst + p)*2;
        float tr = carry[idx], ti = carry[idx+1];
        carry[idx] = sr; carry[idx+1] = si;     // incoming state for chunk c
        float nr = pr*sr - pi*si + tr;
        float ni = pr*si + pi*sr + ti;
        sr = nr; si = ni;
    }
}

__global__ __launch_bounds__(256) void scan3_k(
    float* __restrict__ Bu, const float* __restrict__ lam, const float* __restrict__ carry)
{
    int bc = blockIdx.x;
    int b = bc >> 5, c = bc & 31;
    int p = threadIdx.x;
    float ar = lam[2*p], ai = lam[2*p+1];
    float xr = carry[((size_t)bc*Pst + p)*2];
    float xi = carry[((size_t)bc*Pst + p)*2 + 1];
    float* base = Bu + ((size_t)(b*Lseq + c*64))*(2*Pst);
    #pragma unroll 4
    for (int i = 0; i < 64; ++i) {
        float br = base[(size_t)i*(2*Pst) + p];
        float bi = base[(size_t)i*(2*Pst) + Pst + p];
        float nxr = ar*xr - ai*xi + br;
        float nxi = ar*xi + ai*xr + bi;
        xr = nxr; xi = nxi;
        base[(size_t)i*(2*Pst) + p] = xr;
        base[(size_t)i*(2*Pst) + Pst + p] = xi;
    }
}

// ---------------- 128x128 MFMA bf16 GEMM (fp32 accumulate), 4 waves 2x2, 4x4 frags/wave ----------
// XCD-aware block swizzle (nwg % 8 == 0 for all launch configs).
// A: [M][K] fp32 (AFP32=1, converted in staging) or bf16 (AFP32=0). B: bf16 [N][K]. BK=64.
// EPI 0: C[m,n] = acc                                       (fp32, Bu)
// EPI 1: C[m,d] = ep0[m,d] + gate_a*(acc + Ddiag[d]*u_bf)   ep0=y ep1=mod ep2=Ddiag ep3u=u_bf
// EPI 2: ((ushort*)C)[m,n] = bf16(gelu_tanh(acc + b1[n]))   ep0=b1
// EPI 3: C[m0+m,d] += gate_ff*(acc + b2[d])                 ep0=b2 ep1=mod
#define BKP 72   // padded LDS row stride in bf16 elems (144 B)

template<int EPI, int AFP32>
__global__ __launch_bounds__(256) void gemm_mfma_k(
    const void* __restrict__ Av, const ushort* __restrict__ Bt, float* __restrict__ C,
    int M, int N, int K,
    const float* __restrict__ ep0, const float* __restrict__ ep1,
    const float* __restrict__ ep2, const ushort* __restrict__ ep3u, int m0)
{
    __shared__ ushort As[128*BKP];
    __shared__ ushort Bs[128*BKP];
    int tid = threadIdx.x;
    // XCD swizzle: contiguous chunks of linear block ids per XCD
    int nwg = gridDim.x * gridDim.y;
    int lin = blockIdx.y * gridDim.x + blockIdx.x;
    int cpx = nwg >> 3;
    int swz = (lin & 7) * cpx + (lin >> 3);
    int bx = swz % gridDim.x, by = swz / gridDim.x;

    int w = tid >> 6, l = tid & 63;
    int wr = w >> 1, wc = w & 1;
    int lr = l & 15, lk = l >> 4;

    f32x4 acc[4][4];
    #pragma unroll
    for (int i = 0; i < 4; ++i)
        #pragma unroll
        for (int j = 0; j < 4; ++j)
            #pragma unroll
            for (int q = 0; q < 4; ++q) acc[i][j][q] = 0.f;

    const ushort* Ab = (const ushort*)Av;
    const float*  Af = (const float*)Av;

    for (int kt = 0; kt < K; kt += 64) {
        if (AFP32) {
            #pragma unroll
            for (int j = 0; j < 8; ++j) {
                int idx = tid + j*256;          // 0..2047
                int r = idx >> 4, f4 = idx & 15;
                float4 v = ldg4(Af + (size_t)(by*128 + r)*K + kt + f4*4);
                *reinterpret_cast<ushort4*>(&As[r*BKP + f4*4]) =
                    make_ushort4(f2bf(v.x), f2bf(v.y), f2bf(v.z), f2bf(v.w));
            }
        } else {
            #pragma unroll
            for (int j = 0; j < 4; ++j) {
                int idx = tid + j*256;          // 0..1023
                int r = idx >> 3, kc = idx & 7;
                int4 v = *reinterpret_cast<const int4*>(Ab + (size_t)(by*128 + r)*K + kt + kc*8);
                *reinterpret_cast<int4*>(&As[r*BKP + kc*8]) = v;
            }
        }
        #pragma unroll
        for (int j = 0; j < 4; ++j) {
            int idx = tid + j*256;              // 0..1023
            int r = idx >> 3, kc = idx & 7;
            int4 v = *reinterpret_cast<const int4*>(Bt + (size_t)(bx*128 + r)*K + kt + kc*8);
            *reinterpret_cast<int4*>(&Bs[r*BKP + kc*8]) = v;
        }
        __syncthreads();
        #pragma unroll
        for (int mk = 0; mk < 2; ++mk) {
            bf16x8 a[4], b[4];
            #pragma unroll
            for (int mi = 0; mi < 4; ++mi)
                a[mi] = *reinterpret_cast<bf16x8*>(&As[(wr*64 + mi*16 + lr)*BKP + mk*32 + lk*8]);
            #pragma unroll
            for (int ni = 0; ni < 4; ++ni)
                b[ni] = *reinterpret_cast<bf16x8*>(&Bs[(wc*64 + ni*16 + lr)*BKP + mk*32 + lk*8]);
            #pragma unroll
            for (int mi = 0; mi < 4; ++mi)
                #pragma unroll
                for (int ni = 0; ni < 4; ++ni)
                    acc[mi][ni] = __builtin_amdgcn_mfma_f32_16x16x32_bf16(
                        a[mi], b[ni], acc[mi][ni], 0, 0, 0);
        }
        __syncthreads();
    }

    int row0 = by*128 + wr*64;
    int col0 = bx*128 + wc*64;
    #pragma unroll
    for (int mi = 0; mi < 4; ++mi) {
        #pragma unroll
        for (int ni = 0; ni < 4; ++ni) {
            int n = col0 + ni*16 + lr;
            #pragma unroll
            for (int q = 0; q < 4; ++q) {
                int m = row0 + mi*16 + lk*4 + q;
                float v = acc[mi][ni][q];
                if (EPI == 0) {
                    C[(size_t)m*N + n] = v;
                } else if (EPI == 1) {
                    int b = m >> 11;
                    float g  = ep1[(size_t)b*6144 + 2048 + n];
                    float dd = ep2[n];
                    float uu = bf2f(ep3u[(size_t)m*Dm + n]);
                    C[(size_t)m*Dm + n] = ep0[(size_t)m*Dm + n] + g*(v + dd*uu);
                } else if (EPI == 2) {
                    float x = v + ep0[n];
                    float x3 = x*x*x;
                    float r = 0.5f*x*(1.0f + tanhf(0.7978845608028654f*(x + 0.044715f*x3)));
                    ((ushort*)C)[(size_t)m*N + n] = f2bf(r);
                } else { // EPI 3
                    int gm = m0 + m; int b = gm >> 11;
                    float g = ep1[(size_t)b*6144 + 5120 + n];
                    C[(size_t)gm*Dm + n] += g*(v + ep0[n]);
                }
            }
        }
    }
}

extern "C" void kernel_launch(void* const* d_in, const int* in_sizes, int n_in,
                              void* d_out, int out_size, void* d_ws, size_t ws_size,
                              hipStream_t stream) {
    const float* y      = (const float*)d_in[0];
    const float* t      = (const float*)d_in[1];
    const float* Wm     = (const float*)d_in[2];
    const float* bm     = (const float*)d_in[3];
    const float* Lam_re = (const float*)d_in[4];
    const float* Lam_im = (const float*)d_in[5];
    const float* B_re   = (const float*)d_in[6];
    const float* B_im   = (const float*)d_in[7];
    const float* C_re   = (const float*)d_in[8];
    const float* C_im   = (const float*)d_in[9];
    const float* Ddiag  = (const float*)d_in[10];
    const float* lstep  = (const float*)d_in[11];
    const float* Wc     = (const float*)d_in[12];
    const float* bcn    = (const float*)d_in[13];
    const float* W1     = (const float*)d_in[14];
    const float* b1     = (const float*)d_in[15];
    const float* W2     = (const float*)d_in[16];
    const float* b2     = (const float*)d_in[17];
    float* out = (float*)d_out;
    char* ws = (char*)d_ws;

    // workspace arena (~84 MB)
    ushort* u_bf    = (ushort*)ws;                    // 32 MB: u_bf, later y2_bf (aliased)
    float*  Bu      = (float*)(ws + (32ull<<20));     // 32 MB: Bu -> xs, later h_bf (aliased)
    ushort* Bbar_bf = (ushort*)(ws + (64ull<<20));    // 1 MB  [512][1024]
    ushort* Ccat_bf = (ushort*)(ws + (65ull<<20));    // 1 MB  [1024][512]
    ushort* W1t     = (ushort*)(ws + (66ull<<20));    // 8 MB  [4096][1024]
    ushort* W2t     = (ushort*)(ws + (74ull<<20));    // 8 MB  [1024][4096]
    float*  mod     = (float*)(ws + (82ull<<20));     // 8x6144
    float*  cond    = (float*)(ws + (82ull<<20) + 196608);
    float*  lam     = (float*)(ws + (82ull<<20) + 262144);
    float*  carry   = (float*)(ws + (82ull<<20) + 327680);  // 8*32*256*2 fp32
    ushort* y2_bf = u_bf;
    ushort* h_bf  = (ushort*)Bu;   // 4096x4096 bf16 chunk = 32 MB

    // 0) zero the proj accumulators (mod + cond are contiguous: 196608 + 65536 B)
    hipMemsetAsync(mod, 0, 262144, stream);
    // 1) modulation projections (split-K + atomic)
    proj2_k<<<dim3(24,8),256,0,stream>>>(t, Wm, bm, mod, 6144);
    proj2_k<<<dim3(8,8),256,0,stream>>>(t, Wc, bcn, cond, 2048);
    // 2) SSM parameter prep + weight transposes to bf16 [N][K]
    ssm_setup_k<<<256,256,0,stream>>>(Lam_re, Lam_im, B_re, B_im, lstep, lam, Bbar_bf);
    ccat_k<<<1024,256,0,stream>>>(C_re, C_im, Ccat_bf);
    transp_k<<<dim3(128,32),256,0,stream>>>(W1, W1t, 1024, 4096);
    transp_k<<<dim3(32,128),256,0,stream>>>(W2, W2t, 4096, 1024);
    // 3) LN + AdaLN modulate -> u_bf
    ln_mod_k<0><<<BL,256,0,stream>>>(y, u_bf, mod, nullptr);
    // 4) Bu = u @ Bbar^T   (16384 x 512 x 1024, fp32 out)
    gemm_mfma_k<0,0><<<dim3(4,128),256,0,stream>>>(u_bf, Bbar_bf, Bu, BL, 512, 1024,
                                                   nullptr, nullptr, nullptr, nullptr, 0);
    // 5) complex scan over L (fp32, in-place)
    scan1_k<<<256,256,0,stream>>>(Bu, lam, carry);
    scan2_k<<<8,256,0,stream>>>(carry, lam);
    scan3_k<<<256,256,0,stream>>>(Bu, lam, carry);
    // 6) y1 = y + gate_a*(2Re(xs@C) + Ddiag*u) -> d_out  (16384 x 1024 x 512, A fp32)
    gemm_mfma_k<1,1><<<dim3(8,128),256,0,stream>>>(Bu, Ccat_bf, out, BL, 1024, 512,
                                                   y, mod, Ddiag, u_bf, 0);
    // 7) LN + AdaLN + FF modulate -> y2_bf
    ln_mod_k<1><<<BL,256,0,stream>>>(out, y2_bf, mod, cond);
    // 8) FFN, 4 chunks of 4096 rows
    for (int mc = 0; mc < 4; ++mc) {
        const ushort* y2c = y2_bf + (size_t)mc*4096*Dm;
        gemm_mfma_k<2,0><<<dim3(32,32),256,0,stream>>>(y2c, W1t, (float*)h_bf, 4096, 4096, 1024,
                                                       b1, nullptr, nullptr, nullptr, 0);
        gemm_mfma_k<3,0><<<dim3(8,32),256,0,stream>>>(h_bf, W2t, out, 4096, 1024, 4096,
                                                      b2, mod, nullptr, nullptr, mc*4096);
    }
}